// Round 6
// baseline (347.533 us; speedup 1.0000x reference)
//
#include <hip/hip_runtime.h>
#include <hip/hip_fp16.h>
#include <hip/hip_cooperative_groups.h>
#include <math.h>

namespace cg = cooperative_groups;

// Problem constants (match reference)
#define BB 8
#define NN 2048
#define C_IN 64
#define NCH 64
#define LN_EPS 1e-5f

// ---------------------------------------------------------------------------
// Single cooperative persistent kernel.
// grid = 256 blocks (1 per CU), block = 1024 threads = 16 waves.
// Block blk owns batch b = blk>>5 and row/node range n0 = (blk&31)*64 .. +63
// (4 rows per wave).  Phases separated by grid.sync() only where a
// cross-block dependency exists (3 syncs total):
//   P0 = rowsum(X)          -> sync (pass 1 needs full P0[b,:])
//   P1 = A @ P0, emit A16   -> sync
//   P2 = A16 @ P1           -> sync
//   P3 = A16 @ P2           (local rows only; result kept in LDS)
//   combine + LayerNorm + tanh  (uses LDS pl[0..3] — same-wave data only)
// ---------------------------------------------------------------------------
__global__ __launch_bounds__(1024, 4) void fused_kernel(
        const float* __restrict__ A,      // [B, N, N] fp32
        const float* __restrict__ X,      // [B, N, 64]
        const float* __restrict__ h,      // [4, 64, N]
        const float* __restrict__ gamma,  // [64]
        const float* __restrict__ beta,   // [64]
        float* __restrict__ out,          // [B, N, 64]
        float* __restrict__ P,            // ws: [3][B*N]  (P0, P1, P2)
        __half* __restrict__ A16) {       // ws: [B, N, N] fp16
    cg::grid_group grid = cg::this_grid();

    const int blk  = blockIdx.x;        // 0..255
    const int wave = threadIdx.x >> 6;  // 0..15
    const int lane = threadIdx.x & 63;
    const int b    = blk >> 5;          // 32 blocks per batch
    const int n0   = (blk & 31) * 64;   // row/node base within batch

    __shared__ float p[NN];             // staged p-vector (8 KB)
    __shared__ float pl[4][64];         // this block's P0..P3 slice

    // ---- Phase 0: P0[b,n] = sum_c X[b,n,c]; lane = channel --------------
    #pragma unroll
    for (int i = 0; i < 4; ++i) {
        const int n = n0 + wave * 4 + i;
        float v = X[((size_t)b * NN + n) * C_IN + lane];
        #pragma unroll
        for (int off = 32; off > 0; off >>= 1)
            v += __shfl_down(v, off, 64);
        if (lane == 0) { P[b * NN + n] = v; pl[0][wave * 4 + i] = v; }
    }
    grid.sync();

    // ---- Phase 1: P1 = A @ P0 (fp32), emit A16 --------------------------
    {
        float4* p4 = (float4*)p;
        const float4* src = (const float4*)(P + b * NN);
        if (threadIdx.x < NN / 4) p4[threadIdx.x] = src[threadIdx.x];
        __syncthreads();

        #pragma unroll
        for (int i = 0; i < 4; ++i) {
            const int m = n0 + wave * 4 + i;
            const float4* Ar = (const float4*)(A + (size_t)b * NN * NN + (size_t)m * NN);
            float4 x[8];
            #pragma unroll
            for (int j = 0; j < 8; ++j) x[j] = Ar[j * 64 + lane];

            float acc = 0.f;
            #pragma unroll
            for (int j = 0; j < 8; ++j) {
                float4 pv = p4[j * 64 + lane];
                acc += x[j].x * pv.x + x[j].y * pv.y + x[j].z * pv.z + x[j].w * pv.w;
            }

            float2* A16r = (float2*)(A16 + (size_t)b * NN * NN + (size_t)m * NN);
            #pragma unroll
            for (int j = 0; j < 8; ++j) {
                union { float2 f2; __half2 h2[2]; } u;
                u.h2[0] = __floats2half2_rn(x[j].x, x[j].y);
                u.h2[1] = __floats2half2_rn(x[j].z, x[j].w);
                A16r[j * 64 + lane] = u.f2;
            }

            #pragma unroll
            for (int off = 32; off > 0; off >>= 1)
                acc += __shfl_down(acc, off, 64);
            if (lane == 0) { P[(BB + b) * NN + m] = acc; pl[1][wave * 4 + i] = acc; }
        }
    }
    grid.sync();

    // ---- Phase 2: P2 = A16 @ P1 -----------------------------------------
    {
        float4* p4 = (float4*)p;
        const float4* src = (const float4*)(P + (BB + b) * NN);
        if (threadIdx.x < NN / 4) p4[threadIdx.x] = src[threadIdx.x];
        __syncthreads();

        #pragma unroll
        for (int i = 0; i < 4; ++i) {
            const int m = n0 + wave * 4 + i;
            const float4* Ar = (const float4*)(A16 + (size_t)b * NN * NN + (size_t)m * NN);
            float4 xr[4];
            #pragma unroll
            for (int j = 0; j < 4; ++j) xr[j] = Ar[j * 64 + lane];   // 8 halves each

            float acc = 0.f;
            #pragma unroll
            for (int j = 0; j < 4; ++j) {
                float4 pa = p4[2 * (j * 64 + lane)];
                float4 pb = p4[2 * (j * 64 + lane) + 1];
                const __half2* hx = (const __half2*)&xr[j];
                float2 f0 = __half22float2(hx[0]);
                float2 f1 = __half22float2(hx[1]);
                float2 f2 = __half22float2(hx[2]);
                float2 f3 = __half22float2(hx[3]);
                acc += f0.x * pa.x + f0.y * pa.y + f1.x * pa.z + f1.y * pa.w
                     + f2.x * pb.x + f2.y * pb.y + f3.x * pb.z + f3.y * pb.w;
            }

            #pragma unroll
            for (int off = 32; off > 0; off >>= 1)
                acc += __shfl_down(acc, off, 64);
            if (lane == 0) { P[(2 * BB + b) * NN + m] = acc; pl[2][wave * 4 + i] = acc; }
        }
    }
    grid.sync();

    // ---- Phase 3: P3 = A16 @ P2 (local rows only — no global write) -----
    {
        float4* p4 = (float4*)p;
        const float4* src = (const float4*)(P + (2 * BB + b) * NN);
        if (threadIdx.x < NN / 4) p4[threadIdx.x] = src[threadIdx.x];
        __syncthreads();

        #pragma unroll
        for (int i = 0; i < 4; ++i) {
            const int m = n0 + wave * 4 + i;
            const float4* Ar = (const float4*)(A16 + (size_t)b * NN * NN + (size_t)m * NN);
            float4 xr[4];
            #pragma unroll
            for (int j = 0; j < 4; ++j) xr[j] = Ar[j * 64 + lane];

            float acc = 0.f;
            #pragma unroll
            for (int j = 0; j < 4; ++j) {
                float4 pa = p4[2 * (j * 64 + lane)];
                float4 pb = p4[2 * (j * 64 + lane) + 1];
                const __half2* hx = (const __half2*)&xr[j];
                float2 f0 = __half22float2(hx[0]);
                float2 f1 = __half22float2(hx[1]);
                float2 f2 = __half22float2(hx[2]);
                float2 f3 = __half22float2(hx[3]);
                acc += f0.x * pa.x + f0.y * pa.y + f1.x * pa.z + f1.y * pa.w
                     + f2.x * pb.x + f2.y * pb.y + f3.x * pb.z + f3.y * pb.w;
            }

            #pragma unroll
            for (int off = 32; off > 0; off >>= 1)
                acc += __shfl_down(acc, off, 64);
            if (lane == 0) pl[3][wave * 4 + i] = acc;
        }
    }
    // pl[i][wave*4+j] used below was written by THIS wave in every phase —
    // no cross-wave LDS dependency, so no barrier needed here.

    // ---- Phase 4: combine + LayerNorm + tanh ----------------------------
    #pragma unroll
    for (int i = 0; i < 4; ++i) {
        const int r = wave * 4 + i;
        const int n = n0 + r;

        float y = h[(size_t)(0 * NCH + lane) * NN + n] * pl[0][r]
                + h[(size_t)(1 * NCH + lane) * NN + n] * pl[1][r]
                + h[(size_t)(2 * NCH + lane) * NN + n] * pl[2][r]
                + h[(size_t)(3 * NCH + lane) * NN + n] * pl[3][r];

        float s = y;
        #pragma unroll
        for (int off = 32; off > 0; off >>= 1)
            s += __shfl_xor(s, off, 64);
        const float mean = s * (1.f / NCH);

        float d = y - mean;
        float vs = d * d;
        #pragma unroll
        for (int off = 32; off > 0; off >>= 1)
            vs += __shfl_xor(vs, off, 64);
        const float rstd = rsqrtf(vs * (1.f / NCH) + LN_EPS);

        out[((size_t)b * NN + n) * NCH + lane] = tanhf(d * rstd * gamma[lane] + beta[lane]);
    }
}

// ---------------------------------------------------------------------------
extern "C" void kernel_launch(void* const* d_in, const int* in_sizes, int n_in,
                              void* d_out, int out_size, void* d_ws, size_t ws_size,
                              hipStream_t stream) {
    const float* A     = (const float*)d_in[0];  // [B, N, N]
    const float* X     = (const float*)d_in[1];  // [B, N, 64]
    const float* h     = (const float*)d_in[2];  // [4, 64, N]
    const float* gamma = (const float*)d_in[3];  // [64]
    const float* beta  = (const float*)d_in[4];  // [64]
    float* out = (float*)d_out;                  // [B, N, 64]

    // workspace: P[3][B*N] floats (192 KB), A16 at +1 MB (67 MB)
    float*  P   = (float*)d_ws;
    __half* A16 = (__half*)((char*)d_ws + (1u << 20));

    void* args[] = { (void*)&A, (void*)&X, (void*)&h, (void*)&gamma,
                     (void*)&beta, (void*)&out, (void*)&P, (void*)&A16 };
    hipLaunchCooperativeKernel((void*)fused_kernel, dim3(256), dim3(1024),
                               args, 0, stream);
}

// Round 7
// 246.951 us; speedup vs baseline: 1.4073x; 1.4073x over previous
//
#include <hip/hip_runtime.h>
#include <hip/hip_bf16.h>
#include <hip/hip_fp16.h>
#include <math.h>

// Problem constants (match reference)
#define BB 8
#define NN 2048
#define C_IN 64
#define NCH 64
#define LN_EPS 1e-5f

// ---------------------------------------------------------------------------
// Kernel 1: Xs[b,n] = sum_c X[b,n,c].  one lane per channel, butterfly reduce.
// ---------------------------------------------------------------------------
__global__ void xsum_kernel(const float* __restrict__ X, float* __restrict__ Xs) {
    int row  = (blockIdx.x * blockDim.x + threadIdx.x) >> 6;   // b*NN + n
    int lane = threadIdx.x & 63;
    float v = X[(size_t)row * C_IN + lane];
    #pragma unroll
    for (int off = 32; off > 0; off >>= 1)
        v += __shfl_down(v, off, 64);
    if (lane == 0) Xs[row] = v;
}

// ---------------------------------------------------------------------------
// Kernel 2a: pass 1.  pout[b,m] = dot(A[b,m,:], pin[b,:])  (A fp32)
// AND writes A16[b,m,:] = fp16(A[b,m,:]).
// One row per wave, register-resident p slice, no LDS/barrier.
// ---------------------------------------------------------------------------
__global__ __launch_bounds__(256, 4) void matvec_cvt_kernel(
        const float* __restrict__ A,
        const float* __restrict__ pin,
        float* __restrict__ pout,
        __half* __restrict__ A16) {
    const int b    = blockIdx.y;
    const int wave = threadIdx.x >> 6;
    const int lane = threadIdx.x & 63;
    const int m    = blockIdx.x * 4 + wave;

    const float4* pin4 = (const float4*)(pin + (size_t)b * NN);
    const float4* Ar   = (const float4*)(A + (size_t)b * NN * NN + (size_t)m * NN);

    // burst: 8 independent A loads + 8 independent p loads
    float4 x[8], pr[8];
    #pragma unroll
    for (int j = 0; j < 8; ++j) x[j]  = Ar[j * 64 + lane];
    #pragma unroll
    for (int j = 0; j < 8; ++j) pr[j] = pin4[j * 64 + lane];

    float acc = 0.f;
    #pragma unroll
    for (int j = 0; j < 8; ++j)
        acc += x[j].x * pr[j].x + x[j].y * pr[j].y + x[j].z * pr[j].z + x[j].w * pr[j].w;

    // write fp16 copy of the row: 4 floats -> 8 bytes per j, coalesced
    float2* A16r = (float2*)(A16 + (size_t)b * NN * NN + (size_t)m * NN);
    #pragma unroll
    for (int j = 0; j < 8; ++j) {
        union { float2 f2; __half2 h2[2]; } u;
        u.h2[0] = __floats2half2_rn(x[j].x, x[j].y);
        u.h2[1] = __floats2half2_rn(x[j].z, x[j].w);
        A16r[j * 64 + lane] = u.f2;
    }

    #pragma unroll
    for (int off = 32; off > 0; off >>= 1)
        acc += __shfl_down(acc, off, 64);
    if (lane == 0) pout[(size_t)b * NN + m] = acc;
}

// ---------------------------------------------------------------------------
// Kernel 2b: pass 2.  pout[b,m] = dot(A16[b,m,:], pin[b,:])  (A fp16)
// ---------------------------------------------------------------------------
__global__ __launch_bounds__(256, 4) void matvec16_kernel(
        const __half* __restrict__ A16,
        const float* __restrict__ pin,
        float* __restrict__ pout) {
    const int b    = blockIdx.y;
    const int wave = threadIdx.x >> 6;
    const int lane = threadIdx.x & 63;
    const int m    = blockIdx.x * 4 + wave;

    const float4* pin4 = (const float4*)(pin + (size_t)b * NN);
    const float4* Ar   = (const float4*)(A16 + (size_t)b * NN * NN + (size_t)m * NN);

    float4 xr[4], pa[4], pb[4];
    #pragma unroll
    for (int j = 0; j < 4; ++j) xr[j] = Ar[j * 64 + lane];        // 8 halves each
    #pragma unroll
    for (int j = 0; j < 4; ++j) {
        pa[j] = pin4[2 * (j * 64 + lane)];                         // floats 8k..8k+3
        pb[j] = pin4[2 * (j * 64 + lane) + 1];                     // floats 8k+4..8k+7
    }

    float acc = 0.f;
    #pragma unroll
    for (int j = 0; j < 4; ++j) {
        const __half2* hx = (const __half2*)&xr[j];
        float2 f0 = __half22float2(hx[0]);
        float2 f1 = __half22float2(hx[1]);
        float2 f2 = __half22float2(hx[2]);
        float2 f3 = __half22float2(hx[3]);
        acc += f0.x * pa[j].x + f0.y * pa[j].y + f1.x * pa[j].z + f1.y * pa[j].w
             + f2.x * pb[j].x + f2.y * pb[j].y + f3.x * pb[j].z + f3.y * pb[j].w;
    }

    #pragma unroll
    for (int off = 32; off > 0; off >>= 1)
        acc += __shfl_down(acc, off, 64);
    if (lane == 0) pout[(size_t)b * NN + m] = acc;
}

// ---------------------------------------------------------------------------
// Kernel 2c: pass 3 FUSED with combine + LayerNorm + tanh.
// Wave computes P3[b,n] = dot(A16[b,n,:], P2[b,:]) with an ALL-LANE butterfly
// (every lane ends up with p3), then immediately:
//   y[lane] = h[0,lane,n]*P0 + h[1,lane,n]*P1 + h[2,lane,n]*P2 + h[3,lane,n]*p3
//   LayerNorm across lanes, tanh, coalesced 64-float store.
// Saves a kernel launch, the P3 global round-trip, and the combine dispatch.
// ---------------------------------------------------------------------------
__global__ __launch_bounds__(256, 4) void matvec16_ln_kernel(
        const __half* __restrict__ A16,
        const float* __restrict__ P,      // [3][B*N]  (P0, P1, P2)
        const float* __restrict__ h,      // [4, 64, NN]
        const float* __restrict__ gamma,  // [64]
        const float* __restrict__ beta,   // [64]
        float* __restrict__ out) {        // [BB, NN, 64]
    const int b    = blockIdx.y;
    const int wave = threadIdx.x >> 6;
    const int lane = threadIdx.x & 63;
    const int n    = blockIdx.x * 4 + wave;   // row index == node index

    // ---- P3 = dot(A16[b,n,:], P2[b,:]) ----------------------------------
    const float4* pin4 = (const float4*)(P + (size_t)(2 * BB + b) * NN);
    const float4* Ar   = (const float4*)(A16 + (size_t)b * NN * NN + (size_t)n * NN);

    float4 xr[4], pa[4], pb[4];
    #pragma unroll
    for (int j = 0; j < 4; ++j) xr[j] = Ar[j * 64 + lane];
    #pragma unroll
    for (int j = 0; j < 4; ++j) {
        pa[j] = pin4[2 * (j * 64 + lane)];
        pb[j] = pin4[2 * (j * 64 + lane) + 1];
    }

    float acc = 0.f;
    #pragma unroll
    for (int j = 0; j < 4; ++j) {
        const __half2* hx = (const __half2*)&xr[j];
        float2 f0 = __half22float2(hx[0]);
        float2 f1 = __half22float2(hx[1]);
        float2 f2 = __half22float2(hx[2]);
        float2 f3 = __half22float2(hx[3]);
        acc += f0.x * pa[j].x + f0.y * pa[j].y + f1.x * pa[j].z + f1.y * pa[j].w
             + f2.x * pb[j].x + f2.y * pb[j].y + f3.x * pb[j].z + f3.y * pb[j].w;
    }
    #pragma unroll
    for (int off = 32; off > 0; off >>= 1)        // all-lane reduce
        acc += __shfl_xor(acc, off, 64);
    const float p3 = acc;

    // ---- combine + LayerNorm + tanh -------------------------------------
    const int idx = b * NN + n;
    const float p0 = P[idx];                       // wave-uniform scalars
    const float p1 = P[BB * NN + idx];
    const float p2 = P[2 * BB * NN + idx];

    float y = h[(size_t)(0 * NCH + lane) * NN + n] * p0
            + h[(size_t)(1 * NCH + lane) * NN + n] * p1
            + h[(size_t)(2 * NCH + lane) * NN + n] * p2
            + h[(size_t)(3 * NCH + lane) * NN + n] * p3;

    float s = y;
    #pragma unroll
    for (int off = 32; off > 0; off >>= 1)
        s += __shfl_xor(s, off, 64);
    const float mean = s * (1.f / NCH);

    float d = y - mean;
    float vs = d * d;
    #pragma unroll
    for (int off = 32; off > 0; off >>= 1)
        vs += __shfl_xor(vs, off, 64);
    const float rstd = rsqrtf(vs * (1.f / NCH) + LN_EPS);

    out[(size_t)idx * NCH + lane] = tanhf(d * rstd * gamma[lane] + beta[lane]);
}

// ---------------------------------------------------------------------------
extern "C" void kernel_launch(void* const* d_in, const int* in_sizes, int n_in,
                              void* d_out, int out_size, void* d_ws, size_t ws_size,
                              hipStream_t stream) {
    const float* A     = (const float*)d_in[0];  // [B, N, N]
    const float* X     = (const float*)d_in[1];  // [B, N, 64]
    const float* h     = (const float*)d_in[2];  // [4, 64, N]
    const float* gamma = (const float*)d_in[3];  // [64]
    const float* beta  = (const float*)d_in[4];  // [64]
    float* out = (float*)d_out;                  // [B, N, 64]

    // workspace layout: P[3][B*N] floats (192 KB), A16 at +1 MB (67 MB)
    float*  P   = (float*)d_ws;
    __half* A16 = (__half*)((char*)d_ws + (1u << 20));

    dim3 mv_grid(NN / 4, BB);

    // 1) P0 = rowsum(X)
    xsum_kernel<<<(BB * NN) / 4, 256, 0, stream>>>(X, P);

    // 2) P1 = A @ P0  (fp32 A, emits fp16 copy of A)
    matvec_cvt_kernel<<<mv_grid, 256, 0, stream>>>(A, P, P + BB * NN, A16);

    // 3) P2 = A16 @ P1
    matvec16_kernel<<<mv_grid, 256, 0, stream>>>(
        A16, P + BB * NN, P + 2 * BB * NN);

    // 4) P3 = A16 @ P2, fused with combine + LayerNorm + tanh
    matvec16_ln_kernel<<<mv_grid, 256, 0, stream>>>(
        A16, P, h, gamma, beta, out);
}

// Round 8
// 246.159 us; speedup vs baseline: 1.4118x; 1.0032x over previous
//
#include <hip/hip_runtime.h>
#include <hip/hip_bf16.h>
#include <hip/hip_fp16.h>
#include <math.h>

// Problem constants (match reference)
#define BB 8
#define NN 2048
#define C_IN 64
#define NCH 64
#define LN_EPS 1e-5f

// ---------------------------------------------------------------------------
// Kernel 1: Xs[b,n] = sum_c X[b,n,c].  one lane per channel, butterfly reduce.
// ---------------------------------------------------------------------------
__global__ void xsum_kernel(const float* __restrict__ X, float* __restrict__ Xs) {
    int row  = (blockIdx.x * blockDim.x + threadIdx.x) >> 6;   // b*NN + n
    int lane = threadIdx.x & 63;
    float v = X[(size_t)row * C_IN + lane];
    #pragma unroll
    for (int off = 32; off > 0; off >>= 1)
        v += __shfl_down(v, off, 64);
    if (lane == 0) Xs[row] = v;
}

// ---------------------------------------------------------------------------
// Kernel 2a (pipelined): pass 1.  P1[b,m] = dot(A[b,m,:], P0[b,:]) (A fp32),
// AND writes A16[b,m,:] = fp16(A[b,m,:]).
// 4 rows per wave, register double-buffer: row i+1's 8-float4 burst is in
// flight while row i is dotted/packed/reduced -> loads never drain to zero.
// p staged in LDS once per block (16 rows reuse; ds_read doesn't occupy the
// vmcnt queue).
// ---------------------------------------------------------------------------
__global__ __launch_bounds__(256, 4) void matvec_cvt_kernel(
        const float* __restrict__ A,
        const float* __restrict__ pin,
        float* __restrict__ pout,
        __half* __restrict__ A16) {
    __shared__ float4 p4[NN / 4];       // 8 KB
    const int b = blockIdx.y;

    const float4* src = (const float4*)(pin + (size_t)b * NN);
    p4[threadIdx.x]       = src[threadIdx.x];
    p4[threadIdx.x + 256] = src[threadIdx.x + 256];
    __syncthreads();

    const int wave = threadIdx.x >> 6;
    const int lane = threadIdx.x & 63;
    const int m0   = blockIdx.x * 16 + wave * 4;
    const float* Ab = A + (size_t)b * NN * NN;

    float4 buf[2][8];
    {   // prologue: row m0 burst
        const float4* r = (const float4*)(Ab + (size_t)m0 * NN);
        #pragma unroll
        for (int j = 0; j < 8; ++j) buf[0][j] = r[j * 64 + lane];
    }

    #pragma unroll
    for (int i = 0; i < 4; ++i) {
        const int m = m0 + i;
        if (i < 3) {   // issue next row's burst before consuming current
            const float4* rn = (const float4*)(Ab + (size_t)(m + 1) * NN);
            #pragma unroll
            for (int j = 0; j < 8; ++j) buf[(i + 1) & 1][j] = rn[j * 64 + lane];
        }

        float acc = 0.f;
        #pragma unroll
        for (int j = 0; j < 8; ++j) {
            float4 x  = buf[i & 1][j];
            float4 pv = p4[j * 64 + lane];
            acc += x.x * pv.x + x.y * pv.y + x.z * pv.z + x.w * pv.w;
        }

        float2* A16r = (float2*)(A16 + (size_t)b * NN * NN + (size_t)m * NN);
        #pragma unroll
        for (int j = 0; j < 8; ++j) {
            union { float2 f2; __half2 h2[2]; } u;
            u.h2[0] = __floats2half2_rn(buf[i & 1][j].x, buf[i & 1][j].y);
            u.h2[1] = __floats2half2_rn(buf[i & 1][j].z, buf[i & 1][j].w);
            A16r[j * 64 + lane] = u.f2;
        }

        #pragma unroll
        for (int off = 32; off > 0; off >>= 1)
            acc += __shfl_down(acc, off, 64);
        if (lane == 0) pout[(size_t)b * NN + m] = acc;
    }
}

// ---------------------------------------------------------------------------
// Kernel 2b (pipelined): pass 2.  P2[b,m] = dot(A16[b,m,:], P1[b,:]).
// Same 4-rows-per-wave double-buffer; bursts are 4 float4 (8 halves each).
// ---------------------------------------------------------------------------
__global__ __launch_bounds__(256, 4) void matvec16_kernel(
        const __half* __restrict__ A16,
        const float* __restrict__ pin,
        float* __restrict__ pout) {
    __shared__ float4 p4[NN / 4];
    const int b = blockIdx.y;

    const float4* src = (const float4*)(pin + (size_t)b * NN);
    p4[threadIdx.x]       = src[threadIdx.x];
    p4[threadIdx.x + 256] = src[threadIdx.x + 256];
    __syncthreads();

    const int wave = threadIdx.x >> 6;
    const int lane = threadIdx.x & 63;
    const int m0   = blockIdx.x * 16 + wave * 4;
    const __half* Ab = A16 + (size_t)b * NN * NN;

    float4 buf[2][4];
    {
        const float4* r = (const float4*)(Ab + (size_t)m0 * NN);
        #pragma unroll
        for (int j = 0; j < 4; ++j) buf[0][j] = r[j * 64 + lane];
    }

    #pragma unroll
    for (int i = 0; i < 4; ++i) {
        const int m = m0 + i;
        if (i < 3) {
            const float4* rn = (const float4*)(Ab + (size_t)(m + 1) * NN);
            #pragma unroll
            for (int j = 0; j < 4; ++j) buf[(i + 1) & 1][j] = rn[j * 64 + lane];
        }

        float acc = 0.f;
        #pragma unroll
        for (int j = 0; j < 4; ++j) {
            float4 pa = p4[2 * (j * 64 + lane)];
            float4 pb = p4[2 * (j * 64 + lane) + 1];
            const __half2* hx = (const __half2*)&buf[i & 1][j];
            float2 f0 = __half22float2(hx[0]);
            float2 f1 = __half22float2(hx[1]);
            float2 f2 = __half22float2(hx[2]);
            float2 f3 = __half22float2(hx[3]);
            acc += f0.x * pa.x + f0.y * pa.y + f1.x * pa.z + f1.y * pa.w
                 + f2.x * pb.x + f2.y * pb.y + f3.x * pb.z + f3.y * pb.w;
        }

        #pragma unroll
        for (int off = 32; off > 0; off >>= 1)
            acc += __shfl_down(acc, off, 64);
        if (lane == 0) pout[(size_t)b * NN + m] = acc;
    }
}

// ---------------------------------------------------------------------------
// Kernel 2c (pipelined): pass 3 + combine + LayerNorm + tanh.
// Per row: all-lane xor-reduce gives every lane p3, then lane=channel LN.
// ---------------------------------------------------------------------------
__global__ __launch_bounds__(256, 4) void matvec16_ln_kernel(
        const __half* __restrict__ A16,
        const float* __restrict__ P,      // [3][B*N]  (P0, P1, P2)
        const float* __restrict__ h,      // [4, 64, NN]
        const float* __restrict__ gamma,  // [64]
        const float* __restrict__ beta,   // [64]
        float* __restrict__ out) {        // [BB, NN, 64]
    __shared__ float4 p4[NN / 4];
    const int b = blockIdx.y;

    const float4* src = (const float4*)(P + (size_t)(2 * BB + b) * NN);
    p4[threadIdx.x]       = src[threadIdx.x];
    p4[threadIdx.x + 256] = src[threadIdx.x + 256];
    __syncthreads();

    const int wave = threadIdx.x >> 6;
    const int lane = threadIdx.x & 63;
    const int m0   = blockIdx.x * 16 + wave * 4;
    const __half* Ab = A16 + (size_t)b * NN * NN;

    float4 buf[2][4];
    {
        const float4* r = (const float4*)(Ab + (size_t)m0 * NN);
        #pragma unroll
        for (int j = 0; j < 4; ++j) buf[0][j] = r[j * 64 + lane];
    }

    #pragma unroll
    for (int i = 0; i < 4; ++i) {
        const int m = m0 + i;
        if (i < 3) {
            const float4* rn = (const float4*)(Ab + (size_t)(m + 1) * NN);
            #pragma unroll
            for (int j = 0; j < 4; ++j) buf[(i + 1) & 1][j] = rn[j * 64 + lane];
        }

        float acc = 0.f;
        #pragma unroll
        for (int j = 0; j < 4; ++j) {
            float4 pa = p4[2 * (j * 64 + lane)];
            float4 pb = p4[2 * (j * 64 + lane) + 1];
            const __half2* hx = (const __half2*)&buf[i & 1][j];
            float2 f0 = __half22float2(hx[0]);
            float2 f1 = __half22float2(hx[1]);
            float2 f2 = __half22float2(hx[2]);
            float2 f3 = __half22float2(hx[3]);
            acc += f0.x * pa.x + f0.y * pa.y + f1.x * pa.z + f1.y * pa.w
                 + f2.x * pb.x + f2.y * pb.y + f3.x * pb.z + f3.y * pb.w;
        }
        #pragma unroll
        for (int off = 32; off > 0; off >>= 1)        // all-lane reduce
            acc += __shfl_xor(acc, off, 64);
        const float p3 = acc;

        // ---- combine + LayerNorm + tanh for node n = m ------------------
        const int idx = b * NN + m;
        const float p0 = P[idx];
        const float p1 = P[BB * NN + idx];
        const float p2 = ((const float*)p4)[m & (NN - 1)];   // P2 from LDS

        float y = h[(size_t)(0 * NCH + lane) * NN + m] * p0
                + h[(size_t)(1 * NCH + lane) * NN + m] * p1
                + h[(size_t)(2 * NCH + lane) * NN + m] * p2
                + h[(size_t)(3 * NCH + lane) * NN + m] * p3;

        float s = y;
        #pragma unroll
        for (int off = 32; off > 0; off >>= 1)
            s += __shfl_xor(s, off, 64);
        const float mean = s * (1.f / NCH);

        float d = y - mean;
        float vs = d * d;
        #pragma unroll
        for (int off = 32; off > 0; off >>= 1)
            vs += __shfl_xor(vs, off, 64);
        const float rstd = rsqrtf(vs * (1.f / NCH) + LN_EPS);

        out[(size_t)idx * NCH + lane] = tanhf(d * rstd * gamma[lane] + beta[lane]);
    }
}

// ---------------------------------------------------------------------------
extern "C" void kernel_launch(void* const* d_in, const int* in_sizes, int n_in,
                              void* d_out, int out_size, void* d_ws, size_t ws_size,
                              hipStream_t stream) {
    const float* A     = (const float*)d_in[0];  // [B, N, N]
    const float* X     = (const float*)d_in[1];  // [B, N, 64]
    const float* h     = (const float*)d_in[2];  // [4, 64, N]
    const float* gamma = (const float*)d_in[3];  // [64]
    const float* beta  = (const float*)d_in[4];  // [64]
    float* out = (float*)d_out;                  // [B, N, 64]

    // workspace layout: P[3][B*N] floats (192 KB), A16 at +1 MB (67 MB)
    float*  P   = (float*)d_ws;
    __half* A16 = (__half*)((char*)d_ws + (1u << 20));

    dim3 mv_grid(NN / 16, BB);   // 16 rows per block (4 waves x 4 rows)

    // 1) P0 = rowsum(X)
    xsum_kernel<<<(BB * NN) / 4, 256, 0, stream>>>(X, P);

    // 2) P1 = A @ P0  (fp32 A, emits fp16 copy of A)
    matvec_cvt_kernel<<<mv_grid, 256, 0, stream>>>(A, P, P + BB * NN, A16);

    // 3) P2 = A16 @ P1
    matvec16_kernel<<<mv_grid, 256, 0, stream>>>(
        A16, P + BB * NN, P + 2 * BB * NN);

    // 4) P3 = A16 @ P2, fused with combine + LayerNorm + tanh
    matvec16_ln_kernel<<<mv_grid, 256, 0, stream>>>(
        A16, P, h, gamma, beta, out);
}

// Round 9
// 236.451 us; speedup vs baseline: 1.4698x; 1.0411x over previous
//
#include <hip/hip_runtime.h>
#include <hip/hip_bf16.h>
#include <hip/hip_fp16.h>
#include <math.h>

// Problem constants (match reference)
#define BB 8
#define NN 2048
#define C_IN 64
#define NCH 64
#define LN_EPS 1e-5f

// native clang vector type (works with __builtin_nontemporal_load)
typedef float f4 __attribute__((ext_vector_type(4)));

// ---------------------------------------------------------------------------
// Kernel 1: Xs[b,n] = sum_c X[b,n,c].  one lane per channel, butterfly reduce.
// ---------------------------------------------------------------------------
__global__ void xsum_kernel(const float* __restrict__ X, float* __restrict__ Xs) {
    int row  = (blockIdx.x * blockDim.x + threadIdx.x) >> 6;   // b*NN + n
    int lane = threadIdx.x & 63;
    float v = X[(size_t)row * C_IN + lane];
    #pragma unroll
    for (int off = 32; off > 0; off >>= 1)
        v += __shfl_down(v, off, 64);
    if (lane == 0) Xs[row] = v;
}

// ---------------------------------------------------------------------------
// Kernel 2a: pass 1.  P1[b,m] = dot(A[b,m,:], P0[b,:]) (A fp32),
// AND writes A16[b,m,:] = fp16(A[b,m,:]).
// fp32 A is read NONTEMPORAL (streamed, no LLC allocation) so the A16 copy
// stays resident+clean in the 256 MB LLC -> no 67 MB HBM writeback, and
// passes 2-3 hit LLC.  4 rows/wave, register double-buffer, p in LDS.
// ---------------------------------------------------------------------------
__global__ __launch_bounds__(256, 4) void matvec_cvt_kernel(
        const float* __restrict__ A,
        const float* __restrict__ pin,
        float* __restrict__ pout,
        __half* __restrict__ A16) {
    __shared__ float4 p4[NN / 4];       // 8 KB
    const int b = blockIdx.y;

    const float4* src = (const float4*)(pin + (size_t)b * NN);
    p4[threadIdx.x]       = src[threadIdx.x];
    p4[threadIdx.x + 256] = src[threadIdx.x + 256];
    __syncthreads();

    const int wave = threadIdx.x >> 6;
    const int lane = threadIdx.x & 63;
    const int m0   = blockIdx.x * 16 + wave * 4;
    const float* Ab = A + (size_t)b * NN * NN;

    f4 buf[2][8];
    {   // prologue: row m0 burst (nontemporal)
        const f4* r = (const f4*)(Ab + (size_t)m0 * NN);
        #pragma unroll
        for (int j = 0; j < 8; ++j)
            buf[0][j] = __builtin_nontemporal_load(&r[j * 64 + lane]);
    }

    #pragma unroll
    for (int i = 0; i < 4; ++i) {
        const int m = m0 + i;
        if (i < 3) {   // issue next row's burst before consuming current
            const f4* rn = (const f4*)(Ab + (size_t)(m + 1) * NN);
            #pragma unroll
            for (int j = 0; j < 8; ++j)
                buf[(i + 1) & 1][j] = __builtin_nontemporal_load(&rn[j * 64 + lane]);
        }

        float acc = 0.f;
        #pragma unroll
        for (int j = 0; j < 8; ++j) {
            f4 x      = buf[i & 1][j];
            float4 pv = p4[j * 64 + lane];
            acc += x.x * pv.x + x.y * pv.y + x.z * pv.z + x.w * pv.w;
        }

        // A16 store: REGULAR (we want it allocated in LLC for passes 2-3)
        float2* A16r = (float2*)(A16 + (size_t)b * NN * NN + (size_t)m * NN);
        #pragma unroll
        for (int j = 0; j < 8; ++j) {
            union { float2 f2; __half2 h2[2]; } u;
            u.h2[0] = __floats2half2_rn(buf[i & 1][j].x, buf[i & 1][j].y);
            u.h2[1] = __floats2half2_rn(buf[i & 1][j].z, buf[i & 1][j].w);
            A16r[j * 64 + lane] = u.f2;
        }

        #pragma unroll
        for (int off = 32; off > 0; off >>= 1)
            acc += __shfl_down(acc, off, 64);
        if (lane == 0) pout[(size_t)b * NN + m] = acc;
    }
}

// ---------------------------------------------------------------------------
// Kernel 2b: pass 2.  P2[b,m] = dot(A16[b,m,:], P1[b,:]).  (LLC-served A16)
// ---------------------------------------------------------------------------
__global__ __launch_bounds__(256, 4) void matvec16_kernel(
        const __half* __restrict__ A16,
        const float* __restrict__ pin,
        float* __restrict__ pout) {
    __shared__ float4 p4[NN / 4];
    const int b = blockIdx.y;

    const float4* src = (const float4*)(pin + (size_t)b * NN);
    p4[threadIdx.x]       = src[threadIdx.x];
    p4[threadIdx.x + 256] = src[threadIdx.x + 256];
    __syncthreads();

    const int wave = threadIdx.x >> 6;
    const int lane = threadIdx.x & 63;
    const int m0   = blockIdx.x * 16 + wave * 4;
    const __half* Ab = A16 + (size_t)b * NN * NN;

    float4 buf[2][4];
    {
        const float4* r = (const float4*)(Ab + (size_t)m0 * NN);
        #pragma unroll
        for (int j = 0; j < 4; ++j) buf[0][j] = r[j * 64 + lane];
    }

    #pragma unroll
    for (int i = 0; i < 4; ++i) {
        const int m = m0 + i;
        if (i < 3) {
            const float4* rn = (const float4*)(Ab + (size_t)(m + 1) * NN);
            #pragma unroll
            for (int j = 0; j < 4; ++j) buf[(i + 1) & 1][j] = rn[j * 64 + lane];
        }

        float acc = 0.f;
        #pragma unroll
        for (int j = 0; j < 4; ++j) {
            float4 pa = p4[2 * (j * 64 + lane)];
            float4 pb = p4[2 * (j * 64 + lane) + 1];
            const __half2* hx = (const __half2*)&buf[i & 1][j];
            float2 f0 = __half22float2(hx[0]);
            float2 f1 = __half22float2(hx[1]);
            float2 f2 = __half22float2(hx[2]);
            float2 f3 = __half22float2(hx[3]);
            acc += f0.x * pa.x + f0.y * pa.y + f1.x * pa.z + f1.y * pa.w
                 + f2.x * pb.x + f2.y * pb.y + f3.x * pb.z + f3.y * pb.w;
        }

        #pragma unroll
        for (int off = 32; off > 0; off >>= 1)
            acc += __shfl_down(acc, off, 64);
        if (lane == 0) pout[(size_t)b * NN + m] = acc;
    }
}

// ---------------------------------------------------------------------------
// Kernel 2c: pass 3 + combine + LayerNorm + tanh.
// out store is NONTEMPORAL (4 MB, never re-read).
// ---------------------------------------------------------------------------
__global__ __launch_bounds__(256, 4) void matvec16_ln_kernel(
        const __half* __restrict__ A16,
        const float* __restrict__ P,      // [3][B*N]  (P0, P1, P2)
        const float* __restrict__ h,      // [4, 64, NN]
        const float* __restrict__ gamma,  // [64]
        const float* __restrict__ beta,   // [64]
        float* __restrict__ out) {        // [BB, NN, 64]
    __shared__ float4 p4[NN / 4];
    const int b = blockIdx.y;

    const float4* src = (const float4*)(P + (size_t)(2 * BB + b) * NN);
    p4[threadIdx.x]       = src[threadIdx.x];
    p4[threadIdx.x + 256] = src[threadIdx.x + 256];
    __syncthreads();

    const int wave = threadIdx.x >> 6;
    const int lane = threadIdx.x & 63;
    const int m0   = blockIdx.x * 16 + wave * 4;
    const __half* Ab = A16 + (size_t)b * NN * NN;

    float4 buf[2][4];
    {
        const float4* r = (const float4*)(Ab + (size_t)m0 * NN);
        #pragma unroll
        for (int j = 0; j < 4; ++j) buf[0][j] = r[j * 64 + lane];
    }

    #pragma unroll
    for (int i = 0; i < 4; ++i) {
        const int m = m0 + i;
        if (i < 3) {
            const float4* rn = (const float4*)(Ab + (size_t)(m + 1) * NN);
            #pragma unroll
            for (int j = 0; j < 4; ++j) buf[(i + 1) & 1][j] = rn[j * 64 + lane];
        }

        float acc = 0.f;
        #pragma unroll
        for (int j = 0; j < 4; ++j) {
            float4 pa = p4[2 * (j * 64 + lane)];
            float4 pb = p4[2 * (j * 64 + lane) + 1];
            const __half2* hx = (const __half2*)&buf[i & 1][j];
            float2 f0 = __half22float2(hx[0]);
            float2 f1 = __half22float2(hx[1]);
            float2 f2 = __half22float2(hx[2]);
            float2 f3 = __half22float2(hx[3]);
            acc += f0.x * pa.x + f0.y * pa.y + f1.x * pa.z + f1.y * pa.w
                 + f2.x * pb.x + f2.y * pb.y + f3.x * pb.z + f3.y * pb.w;
        }
        #pragma unroll
        for (int off = 32; off > 0; off >>= 1)        // all-lane reduce
            acc += __shfl_xor(acc, off, 64);
        const float p3 = acc;

        // ---- combine + LayerNorm + tanh for node n = m ------------------
        const int idx = b * NN + m;
        const float p0 = P[idx];
        const float p1 = P[BB * NN + idx];
        const float p2 = ((const float*)p4)[m & (NN - 1)];   // P2 from LDS

        float y = h[(size_t)(0 * NCH + lane) * NN + m] * p0
                + h[(size_t)(1 * NCH + lane) * NN + m] * p1
                + h[(size_t)(2 * NCH + lane) * NN + m] * p2
                + h[(size_t)(3 * NCH + lane) * NN + m] * p3;

        float s = y;
        #pragma unroll
        for (int off = 32; off > 0; off >>= 1)
            s += __shfl_xor(s, off, 64);
        const float mean = s * (1.f / NCH);

        float d = y - mean;
        float vs = d * d;
        #pragma unroll
        for (int off = 32; off > 0; off >>= 1)
            vs += __shfl_xor(vs, off, 64);
        const float rstd = rsqrtf(vs * (1.f / NCH) + LN_EPS);

        __builtin_nontemporal_store(
            tanhf(d * rstd * gamma[lane] + beta[lane]),
            &out[(size_t)idx * NCH + lane]);
    }
}

// ---------------------------------------------------------------------------
extern "C" void kernel_launch(void* const* d_in, const int* in_sizes, int n_in,
                              void* d_out, int out_size, void* d_ws, size_t ws_size,
                              hipStream_t stream) {
    const float* A     = (const float*)d_in[0];  // [B, N, N]
    const float* X     = (const float*)d_in[1];  // [B, N, 64]
    const float* h     = (const float*)d_in[2];  // [4, 64, N]
    const float* gamma = (const float*)d_in[3];  // [64]
    const float* beta  = (const float*)d_in[4];  // [64]
    float* out = (float*)d_out;                  // [B, N, 64]

    // workspace layout: P[3][B*N] floats (192 KB), A16 at +1 MB (67 MB)
    float*  P   = (float*)d_ws;
    __half* A16 = (__half*)((char*)d_ws + (1u << 20));

    dim3 mv_grid(NN / 16, BB);   // 16 rows per block (4 waves x 4 rows)

    // 1) P0 = rowsum(X)
    xsum_kernel<<<(BB * NN) / 4, 256, 0, stream>>>(X, P);

    // 2) P1 = A @ P0  (fp32 A nontemporal, emits fp16 copy of A into LLC)
    matvec_cvt_kernel<<<mv_grid, 256, 0, stream>>>(A, P, P + BB * NN, A16);

    // 3) P2 = A16 @ P1
    matvec16_kernel<<<mv_grid, 256, 0, stream>>>(
        A16, P + BB * NN, P + 2 * BB * NN);

    // 4) P3 = A16 @ P2, fused with combine + LayerNorm + tanh
    matvec16_ln_kernel<<<mv_grid, 256, 0, stream>>>(
        A16, P, h, gamma, beta, out);
}